// Round 11
// baseline (105.588 us; speedup 1.0000x reference)
//
#include <hip/hip_runtime.h>

// MFMA fragment layouts (gfx950, 16x16 family, verified m89):
//   A-frag (M16,K32): lane l holds A[row=l&15][k=(l>>4)*8+e], e=0..7
//   B-frag (K32,N16): lane l holds B[k=(l>>4)*8+e][col=l&15]
//   C/D:              col=l&15, row=(l>>4)*4+reg
//   K=16 variants: same with 4 elems, k=(l>>4)*4+e.
//
// h stored subtiled: hS[jt][et][j'][d'] = h[16*jt+j'][16*et+d'] (16x16 f16 = 512 B).
// ds_read_b64_tr_b16 (verified v6/v8): lane (lg,ll) addr = subtile + lg*128 + ll*8;
// HW transposes within each 16-lane group: elem e = subtile[lg*4+e][ll]
// = h[j0+lg*4+e][e0+ll] — exactly the K16 PV A-frag.
//
// v11 geometry (the only change from v10): 512-thread / 8-wave blocks so TWO
// blocks fit the 16-wave VGPR residency cap (84 arch + 44 acc = 128 total/wave
// -> 4 waves/SIMD; two 10-wave blocks = 20 > 16 kept v10 at 1 block/CU).
// 3 blocks per batch: q in {0,1} -> strips 2w+q (8 waves busy); q==2 ->
// strips 16..18 (3 waves busy). LDS 69 KB x 2 = 138 KB <= 160 KB.
// Per-wave inner code is byte-identical to v10 (proven spill-free, 84 VGPR).

typedef _Float16 half8 __attribute__((ext_vector_type(8)));
typedef _Float16 half4 __attribute__((ext_vector_type(4)));
typedef float f32x4 __attribute__((ext_vector_type(4)));

constexpr int B_ = 256, N_ = 300, E_ = 100;
constexpr float NEGINF = -9e15f;   // reference mask value
constexpr float PADV   = -3e38f;   // padding: exp(PADV - m) == 0 even vs NEGINF max

// LDS: hS subtiled [19][7][16][16] f16 = 68096 B @0 | A16 [4][128] f16 @68096 (1024 B)
constexpr int LDS_BYTES = 68096 + 1024;

__global__ __launch_bounds__(512)
void gat_flash9(const float* __restrict__ H, const int* __restrict__ ADJ,
                const float* __restrict__ A, float* __restrict__ OUT) {
  extern __shared__ char smraw[];
  _Float16* hS  = (_Float16*)smraw;
  _Float16* A16 = (_Float16*)(smraw + 68096);

  const int bid = blockIdx.x;
  const int b = bid / 3, q = bid - 3 * b;       // 3 blocks per batch
  const int tid = threadIdx.x;
  const int w = tid >> 6, lane = tid & 63;
  const int lg = lane >> 4, ll = lane & 15;

  const float* Hb  = H + (size_t)b * (N_ * E_);
  const int*   AJb = ADJ + (size_t)b * (N_ * N_);

  // ---------------- stage h into subtiled LDS (zero-padded) ----------------
  for (int u = tid; u < 304 * 14; u += 512) {
    const int j = u / 14, hr = u % 14;          // hr: 8-half chunk of d (d = hr*8+e)
    half8 v;
#pragma unroll
    for (int e = 0; e < 8; ++e) {
      const int d = hr * 8 + e;
      v[e] = (_Float16)((j < N_ && d < E_) ? Hb[j * E_ + d] : 0.f);
    }
    *(half8*)&hS[(((j >> 4) * 7 + (hr >> 1)) << 8) + ((j & 15) << 4) + ((hr & 1) << 3)] = v;
  }
  if (tid < 64) {
    const int k = tid >> 4, oct = tid & 15;
    half8 v;
#pragma unroll
    for (int e = 0; e < 8; ++e) {
      const int d = oct * 8 + e;
      v[e] = (_Float16)((d < E_) ? A[k * E_ + d] : 0.f);
    }
    *(half8*)&A16[k * 128 + oct * 8] = v;
  }
  __syncthreads();   // only barrier

  const unsigned ldsbase = (unsigned)(size_t)(void*)hS;     // low 32b = LDS offset
  const unsigned trlane  = (unsigned)(ll * 8 + lg * 128);   // per-lane tr addr

  // ================= one wave = one 16-row i-strip =========================
  const int s = (q < 2) ? (2 * w + q) : (16 + w);
  if (s < 19) {
    const int irow = s * 16 + ll;
    const int irc  = irow < N_ ? irow : N_ - 1;

    // ---- G = h_i (.) A_k octets (B-operand fragments) ----
    half8 g[3][4];
    half4 gt[4];
#pragma unroll
    for (int db = 0; db < 3; ++db) {
      const int doct = db * 4 + lg;
      const half8 hi = *(const half8*)&hS[((s * 7 + (doct >> 1)) << 8) + (ll << 4) + ((doct & 1) << 3)];
#pragma unroll
      for (int k = 0; k < 4; ++k)
        g[db][k] = hi * *(const half8*)&A16[k * 128 + doct * 8];
    }
    {
      const half4 hit = *(const half4*)&hS[((s * 7 + 6) << 8) + (ll << 4) + lg * 4];
#pragma unroll
      for (int k = 0; k < 4; ++k)
        gt[k] = hit * *(const half4*)&A16[k * 128 + 96 + lg * 4];
    }

    float m = PADV, lsum = 0.f;
    f32x4 acc[7];
#pragma unroll
    for (int t = 0; t < 7; ++t) acc[t] = (f32x4){0.f, 0.f, 0.f, 0.f};

    const int* ajrow = AJb + (size_t)irc * N_;
    int4 av0 = *(const int4*)(ajrow + lg * 4);          // tile 0 chunk
    int4 av1 = *(const int4*)(ajrow + 16 + lg * 4);     // tile 1 chunk

    // ============ paired j-tiles: jtA=2p, jtB=2p+1 (p=0..8, j<288) =========
    for (int p = 0; p < 9; ++p) {
      const int jtA = 2 * p, jtB = 2 * p + 1;

      // ---- prefetch next pair's adj chunks (clamped in-bounds; exact for
      //      p<8, garbage-but-safe at p=8 where tail reloads anyway) ----
      int jc0 = p * 32 + 32 + lg * 4; if (jc0 > N_ - 4) jc0 = N_ - 4;
      int jc1 = p * 32 + 48 + lg * 4; if (jc1 > N_ - 4) jc1 = N_ - 4;
      const int4 nv0 = *(const int4*)(ajrow + jc0);
      const int4 nv1 = *(const int4*)(ajrow + jc1);

      // ---- scores tile A (4 chains) ----
      f32x4 c0 = {0.f, 0.f, 0.f, 0.f}, c1 = c0, c2 = c0, c3 = c0;
#pragma unroll
      for (int db = 0; db < 3; ++db) {
        const int doct = db * 4 + lg;
        const half8 aj = *(const half8*)&hS[((jtA * 7 + (doct >> 1)) << 8) + (ll << 4) + ((doct & 1) << 3)];
        c0 = __builtin_amdgcn_mfma_f32_16x16x32_f16(aj, g[db][0], c0, 0, 0, 0);
        c1 = __builtin_amdgcn_mfma_f32_16x16x32_f16(aj, g[db][1], c1, 0, 0, 0);
        c2 = __builtin_amdgcn_mfma_f32_16x16x32_f16(aj, g[db][2], c2, 0, 0, 0);
        c3 = __builtin_amdgcn_mfma_f32_16x16x32_f16(aj, g[db][3], c3, 0, 0, 0);
      }
      {
        const half4 ajt = *(const half4*)&hS[((jtA * 7 + 6) << 8) + (ll << 4) + lg * 4];
        c0 = __builtin_amdgcn_mfma_f32_16x16x16f16(ajt, gt[0], c0, 0, 0, 0);
        c1 = __builtin_amdgcn_mfma_f32_16x16x16f16(ajt, gt[1], c1, 0, 0, 0);
        c2 = __builtin_amdgcn_mfma_f32_16x16x16f16(ajt, gt[2], c2, 0, 0, 0);
        c3 = __builtin_amdgcn_mfma_f32_16x16x16f16(ajt, gt[3], c3, 0, 0, 0);
      }
      const int vaA[4] = {av0.x, av0.y, av0.z, av0.w};
      float svA[4];
#pragma unroll
      for (int r = 0; r < 4; ++r) {
        const float e = (vaA[r] == 1) ? c0[r] : (vaA[r] == 2) ? c1[r]
                       : (vaA[r] == 3) ? c2[r] : c3[r];
        svA[r] = (vaA[r] == 0) ? NEGINF : fmaxf(e, 0.2f * e);
      }

      // ---- scores tile B (reuses chain registers after svA extracted) ----
      f32x4 d0 = {0.f, 0.f, 0.f, 0.f}, d1 = d0, d2 = d0, d3 = d0;
#pragma unroll
      for (int db = 0; db < 3; ++db) {
        const int doct = db * 4 + lg;
        const half8 aj = *(const half8*)&hS[((jtB * 7 + (doct >> 1)) << 8) + (ll << 4) + ((doct & 1) << 3)];
        d0 = __builtin_amdgcn_mfma_f32_16x16x32_f16(aj, g[db][0], d0, 0, 0, 0);
        d1 = __builtin_amdgcn_mfma_f32_16x16x32_f16(aj, g[db][1], d1, 0, 0, 0);
        d2 = __builtin_amdgcn_mfma_f32_16x16x32_f16(aj, g[db][2], d2, 0, 0, 0);
        d3 = __builtin_amdgcn_mfma_f32_16x16x32_f16(aj, g[db][3], d3, 0, 0, 0);
      }
      {
        const half4 ajt = *(const half4*)&hS[((jtB * 7 + 6) << 8) + (ll << 4) + lg * 4];
        d0 = __builtin_amdgcn_mfma_f32_16x16x16f16(ajt, gt[0], d0, 0, 0, 0);
        d1 = __builtin_amdgcn_mfma_f32_16x16x16f16(ajt, gt[1], d1, 0, 0, 0);
        d2 = __builtin_amdgcn_mfma_f32_16x16x16f16(ajt, gt[2], d2, 0, 0, 0);
        d3 = __builtin_amdgcn_mfma_f32_16x16x16f16(ajt, gt[3], d3, 0, 0, 0);
      }
      const int vaB[4] = {av1.x, av1.y, av1.z, av1.w};
      float svB[4];
#pragma unroll
      for (int r = 0; r < 4; ++r) {
        const float e = (vaB[r] == 1) ? d0[r] : (vaB[r] == 2) ? d1[r]
                       : (vaB[r] == 3) ? d2[r] : d3[r];
        svB[r] = (vaB[r] == 0) ? NEGINF : fmaxf(e, 0.2f * e);
      }
      av0 = nv0; av1 = nv1;

      // ---- PV h^T fragments: 14 tr-reads; latency covered by softmax ----
      const unsigned trbA = ldsbase + (unsigned)(jtA * 3584) + trlane;
      half4 hfA[7], hfB[7];
#pragma unroll
      for (int t = 0; t < 7; ++t)
        asm volatile("ds_read_b64_tr_b16 %0, %1 offset:%2"
                     : "=v"(hfA[t]) : "v"(trbA), "i"(t * 512));
#pragma unroll
      for (int t = 0; t < 7; ++t)
        asm volatile("ds_read_b64_tr_b16 %0, %1 offset:%2"
                     : "=v"(hfB[t]) : "v"(trbA), "i"(3584 + t * 512));

      // ---- ONE online-softmax update per 32 j (branch-free rescale) ----
      float tmax = fmaxf(fmaxf(fmaxf(svA[0], svA[1]), fmaxf(svA[2], svA[3])),
                         fmaxf(fmaxf(svB[0], svB[1]), fmaxf(svB[2], svB[3])));
      tmax = fmaxf(tmax, __shfl_xor(tmax, 16));
      tmax = fmaxf(tmax, __shfl_xor(tmax, 32));
      const float nm = fmaxf(m, tmax);
      const float f = __expf(m - nm);   // exp(0)==1 exactly when unchanged
      m = nm;
      lsum *= f;
#pragma unroll
      for (int t = 0; t < 7; ++t) {
        acc[t][0] *= f; acc[t][1] *= f; acc[t][2] *= f; acc[t][3] *= f;
      }
      const float pA0 = __expf(svA[0] - m), pA1 = __expf(svA[1] - m);
      const float pA2 = __expf(svA[2] - m), pA3 = __expf(svA[3] - m);
      const float pB0 = __expf(svB[0] - m), pB1 = __expf(svB[1] - m);
      const float pB2 = __expf(svB[2] - m), pB3 = __expf(svB[3] - m);
      lsum += ((pA0 + pA1) + (pA2 + pA3)) + ((pB0 + pB1) + (pB2 + pB3));
      half4 pbA, pbB;
      pbA[0] = (_Float16)pA0; pbA[1] = (_Float16)pA1;
      pbA[2] = (_Float16)pA2; pbA[3] = (_Float16)pA3;
      pbB[0] = (_Float16)pB0; pbB[1] = (_Float16)pB1;
      pbB[2] = (_Float16)pB2; pbB[3] = (_Float16)pB3;

      // ---- PV: one fence for all 14 tr-reads (rule #18) ----
      asm volatile("s_waitcnt lgkmcnt(0)" ::: "memory");
      __builtin_amdgcn_sched_barrier(0);
#pragma unroll
      for (int t = 0; t < 7; ++t) {
        acc[t] = __builtin_amdgcn_mfma_f32_16x16x16f16(hfA[t], pbA, acc[t], 0, 0, 0);
        acc[t] = __builtin_amdgcn_mfma_f32_16x16x16f16(hfB[t], pbB, acc[t], 0, 0, 0);
      }
    }

    // ================= tail tile jt = 18 (j = 288..299) ====================
    {
      const int jt = 18;
      int jc = 288 + lg * 4; if (jc > N_ - 4) jc = N_ - 4;
      const int4 av = *(const int4*)(ajrow + jc);

      f32x4 c0 = {0.f, 0.f, 0.f, 0.f}, c1 = c0, c2 = c0, c3 = c0;
#pragma unroll
      for (int db = 0; db < 3; ++db) {
        const int doct = db * 4 + lg;
        const half8 aj = *(const half8*)&hS[((jt * 7 + (doct >> 1)) << 8) + (ll << 4) + ((doct & 1) << 3)];
        c0 = __builtin_amdgcn_mfma_f32_16x16x32_f16(aj, g[db][0], c0, 0, 0, 0);
        c1 = __builtin_amdgcn_mfma_f32_16x16x32_f16(aj, g[db][1], c1, 0, 0, 0);
        c2 = __builtin_amdgcn_mfma_f32_16x16x32_f16(aj, g[db][2], c2, 0, 0, 0);
        c3 = __builtin_amdgcn_mfma_f32_16x16x32_f16(aj, g[db][3], c3, 0, 0, 0);
      }
      {
        const half4 ajt = *(const half4*)&hS[((jt * 7 + 6) << 8) + (ll << 4) + lg * 4];
        c0 = __builtin_amdgcn_mfma_f32_16x16x16f16(ajt, gt[0], c0, 0, 0, 0);
        c1 = __builtin_amdgcn_mfma_f32_16x16x16f16(ajt, gt[1], c1, 0, 0, 0);
        c2 = __builtin_amdgcn_mfma_f32_16x16x16f16(ajt, gt[2], c2, 0, 0, 0);
        c3 = __builtin_amdgcn_mfma_f32_16x16x16f16(ajt, gt[3], c3, 0, 0, 0);
      }

      const unsigned trb = ldsbase + (unsigned)(jt * 3584) + trlane;
      half4 hf[7];
#pragma unroll
      for (int t = 0; t < 7; ++t)
        asm volatile("ds_read_b64_tr_b16 %0, %1 offset:%2"
                     : "=v"(hf[t]) : "v"(trb), "i"(t * 512));

      const int va[4] = {av.x, av.y, av.z, av.w};
      float sv[4];
#pragma unroll
      for (int r = 0; r < 4; ++r) {
        const float e = (va[r] == 1) ? c0[r] : (va[r] == 2) ? c1[r]
                       : (va[r] == 3) ? c2[r] : c3[r];
        sv[r] = (va[r] == 0) ? NEGINF : fmaxf(e, 0.2f * e);
      }
      if (lg == 3) { sv[0] = PADV; sv[1] = PADV; sv[2] = PADV; sv[3] = PADV; }

      float tmax = fmaxf(fmaxf(sv[0], sv[1]), fmaxf(sv[2], sv[3]));
      tmax = fmaxf(tmax, __shfl_xor(tmax, 16));
      tmax = fmaxf(tmax, __shfl_xor(tmax, 32));
      const float nm = fmaxf(m, tmax);
      const float f = __expf(m - nm);
      m = nm;
      lsum *= f;
#pragma unroll
      for (int t = 0; t < 7; ++t) {
        acc[t][0] *= f; acc[t][1] *= f; acc[t][2] *= f; acc[t][3] *= f;
      }
      const float p0 = __expf(sv[0] - m), p1 = __expf(sv[1] - m);
      const float p2 = __expf(sv[2] - m), p3 = __expf(sv[3] - m);
      lsum += (p0 + p1) + (p2 + p3);
      half4 pb;
      pb[0] = (_Float16)p0; pb[1] = (_Float16)p1;
      pb[2] = (_Float16)p2; pb[3] = (_Float16)p3;

      asm volatile("s_waitcnt lgkmcnt(0)" ::: "memory");
      __builtin_amdgcn_sched_barrier(0);
#pragma unroll
      for (int t = 0; t < 7; ++t)
        acc[t] = __builtin_amdgcn_mfma_f32_16x16x16f16(hf[t], pb, acc[t], 0, 0, 0);
    }

    // ---- epilogue: normalize + store ----
    lsum += __shfl_xor(lsum, 16);
    lsum += __shfl_xor(lsum, 32);
    const float rv = 1.f / lsum;
    if (irow < N_) {
      float* orow = OUT + ((size_t)b * N_ + irow) * E_;
#pragma unroll
      for (int t = 0; t < 7; ++t) {
        const int e0 = t * 16 + lg * 4;
        if (e0 < E_) {
          f32x4 o = acc[t];
          o[0] *= rv; o[1] *= rv; o[2] *= rv; o[3] *= rv;
          *(f32x4*)&orow[e0] = o;
        }
      }
    }
  }
}

extern "C" void kernel_launch(void* const* d_in, const int* in_sizes, int n_in,
                              void* d_out, int out_size, void* d_ws, size_t ws_size,
                              hipStream_t stream) {
  const float* H  = (const float*)d_in[0];
  const int*   AJ = (const int*)d_in[1];
  const float* A  = (const float*)d_in[2];
  float* OUT = (float*)d_out;

  (void)hipFuncSetAttribute(reinterpret_cast<const void*>(gat_flash9),
                            hipFuncAttributeMaxDynamicSharedMemorySize,
                            LDS_BYTES);
  gat_flash9<<<3 * B_, 512, LDS_BYTES, stream>>>(H, AJ, A, OUT);
}

// Round 12
// 70.034 us; speedup vs baseline: 1.5077x; 1.5077x over previous
//
#include <hip/hip_runtime.h>

// MFMA fragment layouts (gfx950, 16x16 family, verified m89):
//   A-frag (M16,K32): lane l holds A[row=l&15][k=(l>>4)*8+e], e=0..7
//   B-frag (K32,N16): lane l holds B[k=(l>>4)*8+e][col=l&15]
//   C/D:              col=l&15, row=(l>>4)*4+reg
//   K=16 variants: same with 4 elems, k=(l>>4)*4+e.
//
// h stored subtiled: hS[jt][et][j'][d'] = h[16*jt+j'][16*et+d'] (16x16 f16 = 512 B).
// ds_read_b64_tr_b16 (verified v6/v8): lane (lg,ll) addr = subtile + lg*128 + ll*8;
// HW transposes within each 16-lane group: elem e = subtile[lg*4+e][ll]
// = h[j0+lg*4+e][e0+ll] — exactly the K16 PV A-frag.
//
// v12 geometry: 768-thread (12-wave) blocks, grid 256 (ONE block per batch).
// Residency model (fits all v3..v11 observations): arch and acc VGPRs round
// separately to 8 → this kernel = ~88 arch + ~48 acc = 136 total → 3 waves/
// SIMD cap = 12 waves/CU. A 12-wave block is EXACTLY the cap. vs v10: +2
// waves/CU, staging once per batch instead of twice, same 2-strip critical
// path (waves 0..6 own strips {w, w+12}, waves 7..11 own {w}).
// VALU cuts vs v10: branched rescale (wave-uniform, skips 28 muls when the
// running max doesn't grow) and exp2-domain scores (A16 pre-scaled by log2e
// at staging -> bare v_exp_f32, no per-exp mul; lrelu commutes with positive
// scaling; masked rows use raw constants so all-masked stays uniform).

typedef _Float16 half8 __attribute__((ext_vector_type(8)));
typedef _Float16 half4 __attribute__((ext_vector_type(4)));
typedef float f32x4 __attribute__((ext_vector_type(4)));

constexpr int B_ = 256, N_ = 300, E_ = 100;
constexpr float NEGINF = -9e15f;   // reference mask value (log2-domain: still -huge)
constexpr float PADV   = -3e38f;   // padding: exp2(PADV - m) == 0 even vs NEGINF max
constexpr float LOG2E  = 1.44269504088896f;

// LDS: hS subtiled [19][7][16][16] f16 = 68096 B @0 | A16 [4][128] f16 @68096 (1024 B)
constexpr int LDS_BYTES = 68096 + 1024;

__global__ __launch_bounds__(768)
void gat_flash10(const float* __restrict__ H, const int* __restrict__ ADJ,
                 const float* __restrict__ A, float* __restrict__ OUT) {
  extern __shared__ char smraw[];
  _Float16* hS  = (_Float16*)smraw;
  _Float16* A16 = (_Float16*)(smraw + 68096);

  const int b = blockIdx.x;                    // one block per batch
  const int tid = threadIdx.x;
  const int w = tid >> 6, lane = tid & 63;
  const int lg = lane >> 4, ll = lane & 15;

  const float* Hb  = H + (size_t)b * (N_ * E_);
  const int*   AJb = ADJ + (size_t)b * (N_ * N_);

  // ---------------- stage h into subtiled LDS (zero-padded) ----------------
  for (int u = tid; u < 304 * 14; u += 768) {
    const int j = u / 14, hr = u % 14;          // hr: 8-half chunk of d (d = hr*8+e)
    half8 v;
#pragma unroll
    for (int e = 0; e < 8; ++e) {
      const int d = hr * 8 + e;
      v[e] = (_Float16)((j < N_ && d < E_) ? Hb[j * E_ + d] : 0.f);
    }
    *(half8*)&hS[(((j >> 4) * 7 + (hr >> 1)) << 8) + ((j & 15) << 4) + ((hr & 1) << 3)] = v;
  }
  if (tid < 64) {
    const int k = tid >> 4, oct = tid & 15;
    half8 v;
#pragma unroll
    for (int e = 0; e < 8; ++e) {
      const int d = oct * 8 + e;
      v[e] = (_Float16)((d < E_) ? A[k * E_ + d] * LOG2E : 0.f);   // log2-domain
    }
    *(half8*)&A16[k * 128 + oct * 8] = v;
  }
  __syncthreads();   // only barrier

  const unsigned ldsbase = (unsigned)(size_t)(void*)hS;     // low 32b = LDS offset
  const unsigned trlane  = (unsigned)(ll * 8 + lg * 128);   // per-lane tr addr

  // ========== strip loop: waves 0..6 own {w, w+12}; waves 7..11 own {w} ====
  for (int s = w; s < 19; s += 12) {
    const int irow = s * 16 + ll;
    const int irc  = irow < N_ ? irow : N_ - 1;

    // ---- G = h_i (.) A_k octets (B-operand fragments) ----
    half8 g[3][4];
    half4 gt[4];
#pragma unroll
    for (int db = 0; db < 3; ++db) {
      const int doct = db * 4 + lg;
      const half8 hi = *(const half8*)&hS[((s * 7 + (doct >> 1)) << 8) + (ll << 4) + ((doct & 1) << 3)];
#pragma unroll
      for (int k = 0; k < 4; ++k)
        g[db][k] = hi * *(const half8*)&A16[k * 128 + doct * 8];
    }
    {
      const half4 hit = *(const half4*)&hS[((s * 7 + 6) << 8) + (ll << 4) + lg * 4];
#pragma unroll
      for (int k = 0; k < 4; ++k)
        gt[k] = hit * *(const half4*)&A16[k * 128 + 96 + lg * 4];
    }

    float m = PADV, lsum = 0.f;
    f32x4 acc[7];
#pragma unroll
    for (int t = 0; t < 7; ++t) acc[t] = (f32x4){0.f, 0.f, 0.f, 0.f};

    const int* ajrow = AJb + (size_t)irc * N_;
    int4 av0 = *(const int4*)(ajrow + lg * 4);          // tile 0 chunk
    int4 av1 = *(const int4*)(ajrow + 16 + lg * 4);     // tile 1 chunk

    // ============ paired j-tiles: jtA=2p, jtB=2p+1 (p=0..8, j<288) =========
    for (int p = 0; p < 9; ++p) {
      const int jtA = 2 * p, jtB = 2 * p + 1;

      // ---- prefetch next pair's adj chunks (clamped in-bounds) ----
      int jc0 = p * 32 + 32 + lg * 4; if (jc0 > N_ - 4) jc0 = N_ - 4;
      int jc1 = p * 32 + 48 + lg * 4; if (jc1 > N_ - 4) jc1 = N_ - 4;
      const int4 nv0 = *(const int4*)(ajrow + jc0);
      const int4 nv1 = *(const int4*)(ajrow + jc1);

      // ---- scores tile A (4 chains) ----
      f32x4 c0 = {0.f, 0.f, 0.f, 0.f}, c1 = c0, c2 = c0, c3 = c0;
#pragma unroll
      for (int db = 0; db < 3; ++db) {
        const int doct = db * 4 + lg;
        const half8 aj = *(const half8*)&hS[((jtA * 7 + (doct >> 1)) << 8) + (ll << 4) + ((doct & 1) << 3)];
        c0 = __builtin_amdgcn_mfma_f32_16x16x32_f16(aj, g[db][0], c0, 0, 0, 0);
        c1 = __builtin_amdgcn_mfma_f32_16x16x32_f16(aj, g[db][1], c1, 0, 0, 0);
        c2 = __builtin_amdgcn_mfma_f32_16x16x32_f16(aj, g[db][2], c2, 0, 0, 0);
        c3 = __builtin_amdgcn_mfma_f32_16x16x32_f16(aj, g[db][3], c3, 0, 0, 0);
      }
      {
        const half4 ajt = *(const half4*)&hS[((jtA * 7 + 6) << 8) + (ll << 4) + lg * 4];
        c0 = __builtin_amdgcn_mfma_f32_16x16x16f16(ajt, gt[0], c0, 0, 0, 0);
        c1 = __builtin_amdgcn_mfma_f32_16x16x16f16(ajt, gt[1], c1, 0, 0, 0);
        c2 = __builtin_amdgcn_mfma_f32_16x16x16f16(ajt, gt[2], c2, 0, 0, 0);
        c3 = __builtin_amdgcn_mfma_f32_16x16x16f16(ajt, gt[3], c3, 0, 0, 0);
      }
      const int vaA[4] = {av0.x, av0.y, av0.z, av0.w};
      float svA[4];
#pragma unroll
      for (int r = 0; r < 4; ++r) {
        const float e = (vaA[r] == 1) ? c0[r] : (vaA[r] == 2) ? c1[r]
                       : (vaA[r] == 3) ? c2[r] : c3[r];
        svA[r] = (vaA[r] == 0) ? NEGINF : fmaxf(e, 0.2f * e);
      }

      // ---- scores tile B (reuses chain registers after svA extracted) ----
      f32x4 d0 = {0.f, 0.f, 0.f, 0.f}, d1 = d0, d2 = d0, d3 = d0;
#pragma unroll
      for (int db = 0; db < 3; ++db) {
        const int doct = db * 4 + lg;
        const half8 aj = *(const half8*)&hS[((jtB * 7 + (doct >> 1)) << 8) + (ll << 4) + ((doct & 1) << 3)];
        d0 = __builtin_amdgcn_mfma_f32_16x16x32_f16(aj, g[db][0], d0, 0, 0, 0);
        d1 = __builtin_amdgcn_mfma_f32_16x16x32_f16(aj, g[db][1], d1, 0, 0, 0);
        d2 = __builtin_amdgcn_mfma_f32_16x16x32_f16(aj, g[db][2], d2, 0, 0, 0);
        d3 = __builtin_amdgcn_mfma_f32_16x16x32_f16(aj, g[db][3], d3, 0, 0, 0);
      }
      {
        const half4 ajt = *(const half4*)&hS[((jtB * 7 + 6) << 8) + (ll << 4) + lg * 4];
        d0 = __builtin_amdgcn_mfma_f32_16x16x16f16(ajt, gt[0], d0, 0, 0, 0);
        d1 = __builtin_amdgcn_mfma_f32_16x16x16f16(ajt, gt[1], d1, 0, 0, 0);
        d2 = __builtin_amdgcn_mfma_f32_16x16x16f16(ajt, gt[2], d2, 0, 0, 0);
        d3 = __builtin_amdgcn_mfma_f32_16x16x16f16(ajt, gt[3], d3, 0, 0, 0);
      }
      const int vaB[4] = {av1.x, av1.y, av1.z, av1.w};
      float svB[4];
#pragma unroll
      for (int r = 0; r < 4; ++r) {
        const float e = (vaB[r] == 1) ? d0[r] : (vaB[r] == 2) ? d1[r]
                       : (vaB[r] == 3) ? d2[r] : d3[r];
        svB[r] = (vaB[r] == 0) ? NEGINF : fmaxf(e, 0.2f * e);
      }
      av0 = nv0; av1 = nv1;

      // ---- PV h^T fragments: 14 tr-reads; latency covered by softmax ----
      const unsigned trbA = ldsbase + (unsigned)(jtA * 3584) + trlane;
      half4 hfA[7], hfB[7];
#pragma unroll
      for (int t = 0; t < 7; ++t)
        asm volatile("ds_read_b64_tr_b16 %0, %1 offset:%2"
                     : "=v"(hfA[t]) : "v"(trbA), "i"(t * 512));
#pragma unroll
      for (int t = 0; t < 7; ++t)
        asm volatile("ds_read_b64_tr_b16 %0, %1 offset:%2"
                     : "=v"(hfB[t]) : "v"(trbA), "i"(3584 + t * 512));

      // ---- ONE online-softmax update per 32 j; branched (uniform) rescale --
      float tmax = fmaxf(fmaxf(fmaxf(svA[0], svA[1]), fmaxf(svA[2], svA[3])),
                         fmaxf(fmaxf(svB[0], svB[1]), fmaxf(svB[2], svB[3])));
      tmax = fmaxf(tmax, __shfl_xor(tmax, 16));
      tmax = fmaxf(tmax, __shfl_xor(tmax, 32));
      if (tmax > m) {                       // uniform: tmax identical across lanes
        const float f = exp2f(m - tmax);
        m = tmax;
        lsum *= f;
#pragma unroll
        for (int t = 0; t < 7; ++t) {
          acc[t][0] *= f; acc[t][1] *= f; acc[t][2] *= f; acc[t][3] *= f;
        }
      }
      const float pA0 = exp2f(svA[0] - m), pA1 = exp2f(svA[1] - m);
      const float pA2 = exp2f(svA[2] - m), pA3 = exp2f(svA[3] - m);
      const float pB0 = exp2f(svB[0] - m), pB1 = exp2f(svB[1] - m);
      const float pB2 = exp2f(svB[2] - m), pB3 = exp2f(svB[3] - m);
      lsum += ((pA0 + pA1) + (pA2 + pA3)) + ((pB0 + pB1) + (pB2 + pB3));
      half4 pbA, pbB;
      pbA[0] = (_Float16)pA0; pbA[1] = (_Float16)pA1;
      pbA[2] = (_Float16)pA2; pbA[3] = (_Float16)pA3;
      pbB[0] = (_Float16)pB0; pbB[1] = (_Float16)pB1;
      pbB[2] = (_Float16)pB2; pbB[3] = (_Float16)pB3;

      // ---- PV: one fence for all 14 tr-reads (rule #18) ----
      asm volatile("s_waitcnt lgkmcnt(0)" ::: "memory");
      __builtin_amdgcn_sched_barrier(0);
#pragma unroll
      for (int t = 0; t < 7; ++t) {
        acc[t] = __builtin_amdgcn_mfma_f32_16x16x16f16(hfA[t], pbA, acc[t], 0, 0, 0);
        acc[t] = __builtin_amdgcn_mfma_f32_16x16x16f16(hfB[t], pbB, acc[t], 0, 0, 0);
      }
    }

    // ================= tail tile jt = 18 (j = 288..299) ====================
    {
      const int jt = 18;
      int jc = 288 + lg * 4; if (jc > N_ - 4) jc = N_ - 4;
      const int4 av = *(const int4*)(ajrow + jc);

      f32x4 c0 = {0.f, 0.f, 0.f, 0.f}, c1 = c0, c2 = c0, c3 = c0;
#pragma unroll
      for (int db = 0; db < 3; ++db) {
        const int doct = db * 4 + lg;
        const half8 aj = *(const half8*)&hS[((jt * 7 + (doct >> 1)) << 8) + (ll << 4) + ((doct & 1) << 3)];
        c0 = __builtin_amdgcn_mfma_f32_16x16x32_f16(aj, g[db][0], c0, 0, 0, 0);
        c1 = __builtin_amdgcn_mfma_f32_16x16x32_f16(aj, g[db][1], c1, 0, 0, 0);
        c2 = __builtin_amdgcn_mfma_f32_16x16x32_f16(aj, g[db][2], c2, 0, 0, 0);
        c3 = __builtin_amdgcn_mfma_f32_16x16x32_f16(aj, g[db][3], c3, 0, 0, 0);
      }
      {
        const half4 ajt = *(const half4*)&hS[((jt * 7 + 6) << 8) + (ll << 4) + lg * 4];
        c0 = __builtin_amdgcn_mfma_f32_16x16x16f16(ajt, gt[0], c0, 0, 0, 0);
        c1 = __builtin_amdgcn_mfma_f32_16x16x16f16(ajt, gt[1], c1, 0, 0, 0);
        c2 = __builtin_amdgcn_mfma_f32_16x16x16f16(ajt, gt[2], c2, 0, 0, 0);
        c3 = __builtin_amdgcn_mfma_f32_16x16x16f16(ajt, gt[3], c3, 0, 0, 0);
      }

      const unsigned trb = ldsbase + (unsigned)(jt * 3584) + trlane;
      half4 hf[7];
#pragma unroll
      for (int t = 0; t < 7; ++t)
        asm volatile("ds_read_b64_tr_b16 %0, %1 offset:%2"
                     : "=v"(hf[t]) : "v"(trb), "i"(t * 512));

      const int va[4] = {av.x, av.y, av.z, av.w};
      float sv[4];
#pragma unroll
      for (int r = 0; r < 4; ++r) {
        const float e = (va[r] == 1) ? c0[r] : (va[r] == 2) ? c1[r]
                       : (va[r] == 3) ? c2[r] : c3[r];
        sv[r] = (va[r] == 0) ? NEGINF : fmaxf(e, 0.2f * e);
      }
      if (lg == 3) { sv[0] = PADV; sv[1] = PADV; sv[2] = PADV; sv[3] = PADV; }

      float tmax = fmaxf(fmaxf(sv[0], sv[1]), fmaxf(sv[2], sv[3]));
      tmax = fmaxf(tmax, __shfl_xor(tmax, 16));
      tmax = fmaxf(tmax, __shfl_xor(tmax, 32));
      if (tmax > m) {
        const float f = exp2f(m - tmax);
        m = tmax;
        lsum *= f;
#pragma unroll
        for (int t = 0; t < 7; ++t) {
          acc[t][0] *= f; acc[t][1] *= f; acc[t][2] *= f; acc[t][3] *= f;
        }
      }
      const float p0 = exp2f(sv[0] - m), p1 = exp2f(sv[1] - m);
      const float p2 = exp2f(sv[2] - m), p3 = exp2f(sv[3] - m);
      lsum += (p0 + p1) + (p2 + p3);
      half4 pb;
      pb[0] = (_Float16)p0; pb[1] = (_Float16)p1;
      pb[2] = (_Float16)p2; pb[3] = (_Float16)p3;

      asm volatile("s_waitcnt lgkmcnt(0)" ::: "memory");
      __builtin_amdgcn_sched_barrier(0);
#pragma unroll
      for (int t = 0; t < 7; ++t)
        acc[t] = __builtin_amdgcn_mfma_f32_16x16x16f16(hf[t], pb, acc[t], 0, 0, 0);
    }

    // ---- epilogue: normalize + store ----
    lsum += __shfl_xor(lsum, 16);
    lsum += __shfl_xor(lsum, 32);
    const float rv = 1.f / lsum;
    if (irow < N_) {
      float* orow = OUT + ((size_t)b * N_ + irow) * E_;
#pragma unroll
      for (int t = 0; t < 7; ++t) {
        const int e0 = t * 16 + lg * 4;
        if (e0 < E_) {
          f32x4 o = acc[t];
          o[0] *= rv; o[1] *= rv; o[2] *= rv; o[3] *= rv;
          *(f32x4*)&orow[e0] = o;
        }
      }
    }
  }
}

extern "C" void kernel_launch(void* const* d_in, const int* in_sizes, int n_in,
                              void* d_out, int out_size, void* d_ws, size_t ws_size,
                              hipStream_t stream) {
  const float* H  = (const float*)d_in[0];
  const int*   AJ = (const int*)d_in[1];
  const float* A  = (const float*)d_in[2];
  float* OUT = (float*)d_out;

  (void)hipFuncSetAttribute(reinterpret_cast<const void*>(gat_flash10),
                            hipFuncAttributeMaxDynamicSharedMemorySize,
                            LDS_BYTES);
  gat_flash10<<<B_, 768, LDS_BYTES, stream>>>(H, AJ, A, OUT);
}

// Round 13
// 68.493 us; speedup vs baseline: 1.5416x; 1.0225x over previous
//
#include <hip/hip_runtime.h>

// MFMA fragment layouts (gfx950, 16x16 family, verified m89):
//   A-frag (M16,K32): lane l holds A[row=l&15][k=(l>>4)*8+e], e=0..7
//   B-frag (K32,N16): lane l holds B[k=(l>>4)*8+e][col=l&15]
//   C/D:              col=l&15, row=(l>>4)*4+reg
//   K=16 variants: same with 4 elems, k=(l>>4)*4+e.
//
// h stored subtiled: hS[jt][et][j'][d'] = h[16*jt+j'][16*et+d'] (16x16 f16 = 512 B).
// ds_read_b64_tr_b16 (verified v6/v8): lane (lg,ll) addr = subtile + lg*128 + ll*8;
// HW transposes within each 16-lane group: elem e = subtile[lg*4+e][ll]
// = h[j0+lg*4+e][e0+ll] — exactly the K16 PV A-frag.
//
// v13 = v12 + deferred-max (T13, v8-proven): common-case per-pair softmax is
// a 7-op per-lane fmax tree + one uniform __any branch — the two __shfl_xor
// and the 28-mul acc rescale only run when the running row-max grows by >8
// (rare after warmup). P <= 2^8 fits fp16 exactly; online-softmax
// self-correction zeroes stale contributions (exp2(-9e15 - nm) == 0).
// Geometry (v12): 768-thread / 12-wave blocks, grid 256 (1 block/batch),
// waves 0..6 own strips {w, w+12}, waves 7..11 own {w}. LDS 69 KB.

typedef _Float16 half8 __attribute__((ext_vector_type(8)));
typedef _Float16 half4 __attribute__((ext_vector_type(4)));
typedef float f32x4 __attribute__((ext_vector_type(4)));

constexpr int B_ = 256, N_ = 300, E_ = 100;
constexpr float NEGINF = -9e15f;   // reference mask value (log2-domain: still -huge)
constexpr float PADV   = -3e38f;   // padding: exp2(PADV - m) == 0 even vs NEGINF max
constexpr float LOG2E  = 1.44269504088896f;

// LDS: hS subtiled [19][7][16][16] f16 = 68096 B @0 | A16 [4][128] f16 @68096 (1024 B)
constexpr int LDS_BYTES = 68096 + 1024;

__global__ __launch_bounds__(768)
void gat_flash11(const float* __restrict__ H, const int* __restrict__ ADJ,
                 const float* __restrict__ A, float* __restrict__ OUT) {
  extern __shared__ char smraw[];
  _Float16* hS  = (_Float16*)smraw;
  _Float16* A16 = (_Float16*)(smraw + 68096);

  const int b = blockIdx.x;                    // one block per batch
  const int tid = threadIdx.x;
  const int w = tid >> 6, lane = tid & 63;
  const int lg = lane >> 4, ll = lane & 15;

  const float* Hb  = H + (size_t)b * (N_ * E_);
  const int*   AJb = ADJ + (size_t)b * (N_ * N_);

  // ---------------- stage h into subtiled LDS (zero-padded) ----------------
  for (int u = tid; u < 304 * 14; u += 768) {
    const int j = u / 14, hr = u % 14;          // hr: 8-half chunk of d (d = hr*8+e)
    half8 v;
#pragma unroll
    for (int e = 0; e < 8; ++e) {
      const int d = hr * 8 + e;
      v[e] = (_Float16)((j < N_ && d < E_) ? Hb[j * E_ + d] : 0.f);
    }
    *(half8*)&hS[(((j >> 4) * 7 + (hr >> 1)) << 8) + ((j & 15) << 4) + ((hr & 1) << 3)] = v;
  }
  if (tid < 64) {
    const int k = tid >> 4, oct = tid & 15;
    half8 v;
#pragma unroll
    for (int e = 0; e < 8; ++e) {
      const int d = oct * 8 + e;
      v[e] = (_Float16)((d < E_) ? A[k * E_ + d] * LOG2E : 0.f);   // log2-domain
    }
    *(half8*)&A16[k * 128 + oct * 8] = v;
  }
  __syncthreads();   // only barrier

  const unsigned ldsbase = (unsigned)(size_t)(void*)hS;     // low 32b = LDS offset
  const unsigned trlane  = (unsigned)(ll * 8 + lg * 128);   // per-lane tr addr

  // ========== strip loop: waves 0..6 own {w, w+12}; waves 7..11 own {w} ====
  for (int s = w; s < 19; s += 12) {
    const int irow = s * 16 + ll;
    const int irc  = irow < N_ ? irow : N_ - 1;

    // ---- G = h_i (.) A_k octets (B-operand fragments) ----
    half8 g[3][4];
    half4 gt[4];
#pragma unroll
    for (int db = 0; db < 3; ++db) {
      const int doct = db * 4 + lg;
      const half8 hi = *(const half8*)&hS[((s * 7 + (doct >> 1)) << 8) + (ll << 4) + ((doct & 1) << 3)];
#pragma unroll
      for (int k = 0; k < 4; ++k)
        g[db][k] = hi * *(const half8*)&A16[k * 128 + doct * 8];
    }
    {
      const half4 hit = *(const half4*)&hS[((s * 7 + 6) << 8) + (ll << 4) + lg * 4];
#pragma unroll
      for (int k = 0; k < 4; ++k)
        gt[k] = hit * *(const half4*)&A16[k * 128 + 96 + lg * 4];
    }

    float m = PADV, lsum = 0.f;
    f32x4 acc[7];
#pragma unroll
    for (int t = 0; t < 7; ++t) acc[t] = (f32x4){0.f, 0.f, 0.f, 0.f};

    const int* ajrow = AJb + (size_t)irc * N_;
    int4 av0 = *(const int4*)(ajrow + lg * 4);          // tile 0 chunk
    int4 av1 = *(const int4*)(ajrow + 16 + lg * 4);     // tile 1 chunk

    // ============ paired j-tiles: jtA=2p, jtB=2p+1 (p=0..8, j<288) =========
    for (int p = 0; p < 9; ++p) {
      const int jtA = 2 * p, jtB = 2 * p + 1;

      // ---- prefetch next pair's adj chunks (clamped in-bounds) ----
      int jc0 = p * 32 + 32 + lg * 4; if (jc0 > N_ - 4) jc0 = N_ - 4;
      int jc1 = p * 32 + 48 + lg * 4; if (jc1 > N_ - 4) jc1 = N_ - 4;
      const int4 nv0 = *(const int4*)(ajrow + jc0);
      const int4 nv1 = *(const int4*)(ajrow + jc1);

      // ---- scores tile A (4 chains) ----
      f32x4 c0 = {0.f, 0.f, 0.f, 0.f}, c1 = c0, c2 = c0, c3 = c0;
#pragma unroll
      for (int db = 0; db < 3; ++db) {
        const int doct = db * 4 + lg;
        const half8 aj = *(const half8*)&hS[((jtA * 7 + (doct >> 1)) << 8) + (ll << 4) + ((doct & 1) << 3)];
        c0 = __builtin_amdgcn_mfma_f32_16x16x32_f16(aj, g[db][0], c0, 0, 0, 0);
        c1 = __builtin_amdgcn_mfma_f32_16x16x32_f16(aj, g[db][1], c1, 0, 0, 0);
        c2 = __builtin_amdgcn_mfma_f32_16x16x32_f16(aj, g[db][2], c2, 0, 0, 0);
        c3 = __builtin_amdgcn_mfma_f32_16x16x32_f16(aj, g[db][3], c3, 0, 0, 0);
      }
      {
        const half4 ajt = *(const half4*)&hS[((jtA * 7 + 6) << 8) + (ll << 4) + lg * 4];
        c0 = __builtin_amdgcn_mfma_f32_16x16x16f16(ajt, gt[0], c0, 0, 0, 0);
        c1 = __builtin_amdgcn_mfma_f32_16x16x16f16(ajt, gt[1], c1, 0, 0, 0);
        c2 = __builtin_amdgcn_mfma_f32_16x16x16f16(ajt, gt[2], c2, 0, 0, 0);
        c3 = __builtin_amdgcn_mfma_f32_16x16x16f16(ajt, gt[3], c3, 0, 0, 0);
      }
      const int vaA[4] = {av0.x, av0.y, av0.z, av0.w};
      float svA[4];
#pragma unroll
      for (int r = 0; r < 4; ++r) {
        const float e = (vaA[r] == 1) ? c0[r] : (vaA[r] == 2) ? c1[r]
                       : (vaA[r] == 3) ? c2[r] : c3[r];
        svA[r] = (vaA[r] == 0) ? NEGINF : fmaxf(e, 0.2f * e);
      }

      // ---- scores tile B (reuses chain registers after svA extracted) ----
      f32x4 d0 = {0.f, 0.f, 0.f, 0.f}, d1 = d0, d2 = d0, d3 = d0;
#pragma unroll
      for (int db = 0; db < 3; ++db) {
        const int doct = db * 4 + lg;
        const half8 aj = *(const half8*)&hS[((jtB * 7 + (doct >> 1)) << 8) + (ll << 4) + ((doct & 1) << 3)];
        d0 = __builtin_amdgcn_mfma_f32_16x16x32_f16(aj, g[db][0], d0, 0, 0, 0);
        d1 = __builtin_amdgcn_mfma_f32_16x16x32_f16(aj, g[db][1], d1, 0, 0, 0);
        d2 = __builtin_amdgcn_mfma_f32_16x16x32_f16(aj, g[db][2], d2, 0, 0, 0);
        d3 = __builtin_amdgcn_mfma_f32_16x16x32_f16(aj, g[db][3], d3, 0, 0, 0);
      }
      {
        const half4 ajt = *(const half4*)&hS[((jtB * 7 + 6) << 8) + (ll << 4) + lg * 4];
        d0 = __builtin_amdgcn_mfma_f32_16x16x16f16(ajt, gt[0], d0, 0, 0, 0);
        d1 = __builtin_amdgcn_mfma_f32_16x16x16f16(ajt, gt[1], d1, 0, 0, 0);
        d2 = __builtin_amdgcn_mfma_f32_16x16x16f16(ajt, gt[2], d2, 0, 0, 0);
        d3 = __builtin_amdgcn_mfma_f32_16x16x16f16(ajt, gt[3], d3, 0, 0, 0);
      }
      const int vaB[4] = {av1.x, av1.y, av1.z, av1.w};
      float svB[4];
#pragma unroll
      for (int r = 0; r < 4; ++r) {
        const float e = (vaB[r] == 1) ? d0[r] : (vaB[r] == 2) ? d1[r]
                       : (vaB[r] == 3) ? d2[r] : d3[r];
        svB[r] = (vaB[r] == 0) ? NEGINF : fmaxf(e, 0.2f * e);
      }
      av0 = nv0; av1 = nv1;

      // ---- PV h^T fragments: 14 tr-reads; latency covered by softmax ----
      const unsigned trbA = ldsbase + (unsigned)(jtA * 3584) + trlane;
      half4 hfA[7], hfB[7];
#pragma unroll
      for (int t = 0; t < 7; ++t)
        asm volatile("ds_read_b64_tr_b16 %0, %1 offset:%2"
                     : "=v"(hfA[t]) : "v"(trbA), "i"(t * 512));
#pragma unroll
      for (int t = 0; t < 7; ++t)
        asm volatile("ds_read_b64_tr_b16 %0, %1 offset:%2"
                     : "=v"(hfB[t]) : "v"(trbA), "i"(3584 + t * 512));

      // ---- deferred online softmax: common case = per-lane tree + __any ----
      const float lmax = fmaxf(fmaxf(fmaxf(svA[0], svA[1]), fmaxf(svA[2], svA[3])),
                               fmaxf(fmaxf(svB[0], svB[1]), fmaxf(svB[2], svB[3])));
      if (__any(lmax > m + 8.f)) {          // rare after warmup; P <= 2^8 in fp16
        float tmax = fmaxf(lmax, __shfl_xor(lmax, 16));
        tmax = fmaxf(tmax, __shfl_xor(tmax, 32));
        const float nm = fmaxf(m, tmax);
        const float f = exp2f(m - nm);      // ==0 exactly when m was -huge
        m = nm;
        lsum *= f;
#pragma unroll
        for (int t = 0; t < 7; ++t) {
          acc[t][0] *= f; acc[t][1] *= f; acc[t][2] *= f; acc[t][3] *= f;
        }
      }
      const float pA0 = exp2f(svA[0] - m), pA1 = exp2f(svA[1] - m);
      const float pA2 = exp2f(svA[2] - m), pA3 = exp2f(svA[3] - m);
      const float pB0 = exp2f(svB[0] - m), pB1 = exp2f(svB[1] - m);
      const float pB2 = exp2f(svB[2] - m), pB3 = exp2f(svB[3] - m);
      lsum += ((pA0 + pA1) + (pA2 + pA3)) + ((pB0 + pB1) + (pB2 + pB3));
      half4 pbA, pbB;
      pbA[0] = (_Float16)pA0; pbA[1] = (_Float16)pA1;
      pbA[2] = (_Float16)pA2; pbA[3] = (_Float16)pA3;
      pbB[0] = (_Float16)pB0; pbB[1] = (_Float16)pB1;
      pbB[2] = (_Float16)pB2; pbB[3] = (_Float16)pB3;

      // ---- PV: one fence for all 14 tr-reads (rule #18) ----
      asm volatile("s_waitcnt lgkmcnt(0)" ::: "memory");
      __builtin_amdgcn_sched_barrier(0);
#pragma unroll
      for (int t = 0; t < 7; ++t) {
        acc[t] = __builtin_amdgcn_mfma_f32_16x16x16f16(hfA[t], pbA, acc[t], 0, 0, 0);
        acc[t] = __builtin_amdgcn_mfma_f32_16x16x16f16(hfB[t], pbB, acc[t], 0, 0, 0);
      }
    }

    // ================= tail tile jt = 18 (j = 288..299) ====================
    {
      const int jt = 18;
      int jc = 288 + lg * 4; if (jc > N_ - 4) jc = N_ - 4;
      const int4 av = *(const int4*)(ajrow + jc);

      f32x4 c0 = {0.f, 0.f, 0.f, 0.f}, c1 = c0, c2 = c0, c3 = c0;
#pragma unroll
      for (int db = 0; db < 3; ++db) {
        const int doct = db * 4 + lg;
        const half8 aj = *(const half8*)&hS[((jt * 7 + (doct >> 1)) << 8) + (ll << 4) + ((doct & 1) << 3)];
        c0 = __builtin_amdgcn_mfma_f32_16x16x32_f16(aj, g[db][0], c0, 0, 0, 0);
        c1 = __builtin_amdgcn_mfma_f32_16x16x32_f16(aj, g[db][1], c1, 0, 0, 0);
        c2 = __builtin_amdgcn_mfma_f32_16x16x32_f16(aj, g[db][2], c2, 0, 0, 0);
        c3 = __builtin_amdgcn_mfma_f32_16x16x32_f16(aj, g[db][3], c3, 0, 0, 0);
      }
      {
        const half4 ajt = *(const half4*)&hS[((jt * 7 + 6) << 8) + (ll << 4) + lg * 4];
        c0 = __builtin_amdgcn_mfma_f32_16x16x16f16(ajt, gt[0], c0, 0, 0, 0);
        c1 = __builtin_amdgcn_mfma_f32_16x16x16f16(ajt, gt[1], c1, 0, 0, 0);
        c2 = __builtin_amdgcn_mfma_f32_16x16x16f16(ajt, gt[2], c2, 0, 0, 0);
        c3 = __builtin_amdgcn_mfma_f32_16x16x16f16(ajt, gt[3], c3, 0, 0, 0);
      }

      const unsigned trb = ldsbase + (unsigned)(jt * 3584) + trlane;
      half4 hf[7];
#pragma unroll
      for (int t = 0; t < 7; ++t)
        asm volatile("ds_read_b64_tr_b16 %0, %1 offset:%2"
                     : "=v"(hf[t]) : "v"(trb), "i"(t * 512));

      const int va[4] = {av.x, av.y, av.z, av.w};
      float sv[4];
#pragma unroll
      for (int r = 0; r < 4; ++r) {
        const float e = (va[r] == 1) ? c0[r] : (va[r] == 2) ? c1[r]
                       : (va[r] == 3) ? c2[r] : c3[r];
        sv[r] = (va[r] == 0) ? NEGINF : fmaxf(e, 0.2f * e);
      }
      if (lg == 3) { sv[0] = PADV; sv[1] = PADV; sv[2] = PADV; sv[3] = PADV; }

      const float lmax = fmaxf(fmaxf(sv[0], sv[1]), fmaxf(sv[2], sv[3]));
      if (__any(lmax > m + 8.f)) {
        float tmax = fmaxf(lmax, __shfl_xor(lmax, 16));
        tmax = fmaxf(tmax, __shfl_xor(tmax, 32));
        const float nm = fmaxf(m, tmax);
        const float f = exp2f(m - nm);
        m = nm;
        lsum *= f;
#pragma unroll
        for (int t = 0; t < 7; ++t) {
          acc[t][0] *= f; acc[t][1] *= f; acc[t][2] *= f; acc[t][3] *= f;
        }
      }
      const float p0 = exp2f(sv[0] - m), p1 = exp2f(sv[1] - m);
      const float p2 = exp2f(sv[2] - m), p3 = exp2f(sv[3] - m);
      lsum += (p0 + p1) + (p2 + p3);
      half4 pb;
      pb[0] = (_Float16)p0; pb[1] = (_Float16)p1;
      pb[2] = (_Float16)p2; pb[3] = (_Float16)p3;

      asm volatile("s_waitcnt lgkmcnt(0)" ::: "memory");
      __builtin_amdgcn_sched_barrier(0);
#pragma unroll
      for (int t = 0; t < 7; ++t)
        acc[t] = __builtin_amdgcn_mfma_f32_16x16x16f16(hf[t], pb, acc[t], 0, 0, 0);
    }

    // ---- epilogue: normalize + store ----
    lsum += __shfl_xor(lsum, 16);
    lsum += __shfl_xor(lsum, 32);
    const float rv = 1.f / lsum;
    if (irow < N_) {
      float* orow = OUT + ((size_t)b * N_ + irow) * E_;
#pragma unroll
      for (int t = 0; t < 7; ++t) {
        const int e0 = t * 16 + lg * 4;
        if (e0 < E_) {
          f32x4 o = acc[t];
          o[0] *= rv; o[1] *= rv; o[2] *= rv; o[3] *= rv;
          *(f32x4*)&orow[e0] = o;
        }
      }
    }
  }
}

extern "C" void kernel_launch(void* const* d_in, const int* in_sizes, int n_in,
                              void* d_out, int out_size, void* d_ws, size_t ws_size,
                              hipStream_t stream) {
  const float* H  = (const float*)d_in[0];
  const int*   AJ = (const int*)d_in[1];
  const float* A  = (const float*)d_in[2];
  float* OUT = (float*)d_out;

  (void)hipFuncSetAttribute(reinterpret_cast<const void*>(gat_flash11),
                            hipFuncAttributeMaxDynamicSharedMemorySize,
                            LDS_BYTES);
  gat_flash11<<<B_, 768, LDS_BYTES, stream>>>(H, AJ, A, OUT);
}